// Round 10
// baseline (1366.472 us; speedup 1.0000x reference)
//
#include <hip/hip_runtime.h>
#include <hip/hip_bf16.h>

#define HLAT 181
#define WLON 360
#define HW (HLAT * WLON)
#define HPAD 188
#define WPAD 368
#define PCH ((size_t)HPAD * WPAD * 16)   // ushorts per chunk-plane

typedef __attribute__((ext_vector_type(8)))  short short8v;
typedef __attribute__((ext_vector_type(16))) float f32x16;

static __device__ __forceinline__ ushort bf16_hi_bits(float f) {
  union { float f; unsigned u; } c; c.f = f;
  unsigned u = c.u;
  unsigned rounded = u + 0x7FFF + ((u >> 16) & 1);  // RNE
  return (ushort)(rounded >> 16);
}
static __device__ __forceinline__ float bf16_to_f(ushort b) {
  union { unsigned u; float f; } c; c.u = ((unsigned)b) << 16;
  return c.f;
}

// ---------------- kernel 0: weight prep ----------------
// w2f entry idx = (tap*8+ch)*4 + m*2 + p ; each entry = 64 short8 (lane l)
//   lane l, j: part p of w2[oc=m*32+(l&31)][ci=ch*16+(l>>5)*8+j][tap]
// w1t[o][28]: padded copy of w1 (col 27 = 0). w3t[c*25+ij][4].
__global__ __launch_bounds__(256) void k_tw(const float* __restrict__ w2,
                                            const float* __restrict__ w3,
                                            const float* __restrict__ w1,
                                            ushort* __restrict__ w2f,
                                            float* __restrict__ w3t,
                                            float* __restrict__ w1t) {
  int idx = blockIdx.x * 256 + threadIdx.x;
  if (idx < 51200) {
    int l   = idx & 63;
    int p   = (idx >> 6) & 1;
    int m   = (idx >> 7) & 1;
    int ch  = (idx >> 8) & 7;
    int tap = idx >> 11;
    int oc  = m * 32 + (l & 31);
    int ci0 = ch * 16 + (l >> 5) * 8;
#pragma unroll
    for (int j = 0; j < 8; ++j) {
      float f = w2[(oc * 128 + ci0 + j) * 25 + tap];
      ushort hi = bf16_hi_bits(f);
      ushort v;
      if (p == 0) v = hi;
      else        v = bf16_hi_bits(f - bf16_to_f(hi));
      w2f[(size_t)idx * 8 + j] = v;
    }
  }
  if (idx < 1600 * 4) {
    int ck = idx >> 2, o = idx & 3;
    int c = ck / 25, ij = ck % 25;
    w3t[idx] = (o < 3) ? w3[(o * 64 + c) * 25 + ij] : 0.f;
  }
  if (idx < 3584) {
    int o = idx / 28, q = idx % 28;
    w1t[idx] = (q < 27) ? w1[o * 27 + q] : 0.f;
  }
}

// ---------------- zero ONLY the pad ring pixels (4024 per plane) ----------
__global__ __launch_bounds__(256) void k_zring(ushort* __restrict__ h1s) {
  const int i = blockIdx.x * 256 + threadIdx.x;
  if (i >= 4024) return;
  int row, col;
  if (i < 736)       { row = i / 368;              col = i % 368; }
  else if (i < 2576) { int p = i - 736;  row = 183 + p / 368; col = p % 368; }
  else if (i < 2938) { int p = i - 2576; row = 2 + p % 181;   col = p / 181; }
  else               { int p = i - 2938; row = 2 + p % 181;   col = 362 + p / 181; }
  short8v z = {0, 0, 0, 0, 0, 0, 0, 0};
  short8v* d = (short8v*)(h1s + (size_t)blockIdx.y * PCH + ((size_t)row * 368 + col) * 16);
  d[0] = z; d[1] = z;
}

// ---------------- kernel 1: disco conv + w1 GEMM + relu (LDS-free) -------
// 3 px/thread: block 128 (120 active), px = tid, tid+120, tid+240.
// Rationale: the o-phase's 896 wave-uniform s_load chain is per-WAVE cost;
// 3 px/thread cuts wave count 4344->2896 and triples FMA to hide latency.
__global__ __launch_bounds__(128, 2) void k_l1(const float* __restrict__ x,
    const float* __restrict__ psi, const float* __restrict__ quad,
    const float* __restrict__ w1t, const float* __restrict__ b1,
    ushort* __restrict__ h1s, int b0) {
  const int h = blockIdx.x;
  const int bi = blockIdx.y;
  const int b = b0 + bi;
  const int tid = threadIdx.x;
  if (tid >= 120) return;

  float z[3][28];
#pragma unroll
  for (int pp = 0; pp < 3; ++pp)
#pragma unroll
    for (int q = 0; q < 28; ++q) z[pp][q] = 0.f;

#pragma unroll 1
  for (int i = 0; i < 5; ++i) {
    int hi = h + i - 2;
    hi = hi < 0 ? 0 : (hi >= HLAT ? HLAT - 1 : hi);
    const float qv = quad[hi];                 // uniform -> scalar load
    float pv[45];                              // uniform psi slice for this i
#pragma unroll
    for (int kk = 0; kk < 9; ++kk)
#pragma unroll
      for (int j = 0; j < 5; ++j)
        pv[kk * 5 + j] = psi[((size_t)(kk * HLAT + h)) * 25 + i * 5 + j];
#pragma unroll
    for (int c = 0; c < 3; ++c) {
      const float* row = x + ((size_t)(b * 3 + c) * HLAT + hi) * WLON;
      float v[3][5];
#pragma unroll
      for (int pp = 0; pp < 3; ++pp)
#pragma unroll
        for (int j = 0; j < 5; ++j) {
          int wj = tid + pp * 120 + j - 2;
          wj = wj < 0 ? wj + WLON : (wj >= WLON ? wj - WLON : wj);
          v[pp][j] = row[wj] * qv;
        }
#pragma unroll
      for (int kk = 0; kk < 9; ++kk) {
#pragma unroll
        for (int pp = 0; pp < 3; ++pp) {
          float a = 0.f;
#pragma unroll
          for (int j = 0; j < 5; ++j) a += pv[kk * 5 + j] * v[pp][j];
          z[pp][c * 9 + kk] += a;
        }
      }
    }
  }
#pragma unroll
  for (int pp = 0; pp < 3; ++pp) z[pp][27] = 0.f;

  ushort* base = h1s + (size_t)bi * 16 * PCH;
  size_t poff[3];
#pragma unroll
  for (int pp = 0; pp < 3; ++pp)
    poff[pp] = ((size_t)(h + 2) * WPAD + (tid + pp * 120 + 2)) * 16;

  for (int chv = 0; chv < 8; ++chv) {
    union { ushort u[16]; short8v v[2]; } hb[3], lb[3];
#pragma unroll
    for (int oo = 0; oo < 16; ++oo) {
      const int o = chv * 16 + oo;
      float a[3];
      const float bias = b1[o];                // uniform -> scalar load
      a[0] = bias; a[1] = bias; a[2] = bias;
#pragma unroll
      for (int q4 = 0; q4 < 7; ++q4) {
        const float4 wv = *(const float4*)&w1t[o * 28 + q4 * 4];  // uniform
#pragma unroll
        for (int pp = 0; pp < 3; ++pp)
          a[pp] += wv.x * z[pp][q4 * 4 + 0] + wv.y * z[pp][q4 * 4 + 1] +
                   wv.z * z[pp][q4 * 4 + 2] + wv.w * z[pp][q4 * 4 + 3];
      }
#pragma unroll
      for (int pp = 0; pp < 3; ++pp) {
        const float r = fmaxf(a[pp], 0.f);
        const ushort hbit = bf16_hi_bits(r);
        hb[pp].u[oo] = hbit;
        lb[pp].u[oo] = bf16_hi_bits(r - bf16_to_f(hbit));
      }
    }
    ushort* phi = base + (size_t)chv * PCH;            // part 0
    ushort* plo = base + (size_t)(8 + chv) * PCH;      // part 1
#pragma unroll
    for (int pp = 0; pp < 3; ++pp) {
      *(short8v*)(phi + poff[pp])     = hb[pp].v[0];
      *(short8v*)(phi + poff[pp] + 8) = hb[pp].v[1];
      *(short8v*)(plo + poff[pp])     = lb[pp].v[0];
      *(short8v*)(plo + poff[pp] + 8) = lb[pp].v[1];
    }
  }
}

// ---------------- kernel 2: conv 128->64 via bf16x3 MFMA (R9 form) --------
// grid (12, 23, bc) block 256 (4 waves = m-half x row-group).
// Tile: 64oc x 8rows x 32cols; wave = 32oc x 4rows x 32cols. 2 blocks/CU.
__global__ __launch_bounds__(256, 2) void k_conv2(const ushort* __restrict__ h1s,
    const ushort* __restrict__ w2f, const float* __restrict__ b2,
    float* __restrict__ h2) {
  __shared__ ushort act[2][2][12][40][16];  // [buf][part][row][col][ci16] = 61440 B
  const int x0 = blockIdx.x * 32;
  const int y0 = blockIdx.y * 8;
  const int bi = blockIdx.z;
  const int tid = threadIdx.x;
  const int wv = tid >> 6;
  const int m  = wv >> 1;         // oc half (0..1)
  const int wr = wv & 1;          // row-group (0..1)
  const int l = tid & 63;
  const int l31 = l & 31;
  const int q8 = (l >> 5) * 8;

  f32x16 acc[4];
#pragma unroll
  for (int r = 0; r < 4; ++r)
#pragma unroll
    for (int e = 0; e < 16; ++e) acc[r][e] = 0.f;

  const short8v* wf = (const short8v*)w2f;
  const ushort* pbase = h1s + (size_t)bi * 16 * PCH;

  auto stage = [&](int buf, int ch) {
#pragma unroll
    for (int s = 0; s < 12; ++s) {
      const int k = wv * 12 + s;          // 0..47
      const int part = k / 24;
      const int rem = k - part * 24;
      const int t = rem >> 1;             // row 0..11
      const int slot = rem & 1;
      const ushort* pl = pbase + (size_t)(part * 8 + ch) * PCH;
      if (slot == 0) {
        const ushort* g = pl + ((size_t)(y0 + t) * WPAD + (x0 + (l >> 1))) * 16 + (l & 1) * 8;
        __builtin_amdgcn_global_load_lds(
            (const __attribute__((address_space(1))) unsigned int*)g,
            (__attribute__((address_space(3))) unsigned int*)&act[buf][part][t][0][0], 16, 0, 0);
      } else {
        const ushort* g = pl + ((size_t)(y0 + t) * WPAD + (x0 + 32 + (l >> 3))) * 16 + (l & 7) * 2;
        __builtin_amdgcn_global_load_lds(
            (const __attribute__((address_space(1))) unsigned int*)g,
            (__attribute__((address_space(3))) unsigned int*)&act[buf][part][t][32][0], 4, 0, 0);
      }
    }
  };

  // prologue
  stage(0, 0);
  asm volatile("s_waitcnt vmcnt(0)" ::: "memory");
  __syncthreads();

#pragma unroll 1
  for (int ch = 0; ch < 8; ++ch) {
    const int cur = ch & 1;
    if (ch < 7) stage(cur ^ 1, ch + 1);   // prefetch next chunk (other buffer)
#pragma unroll 1
    for (int dj = 0; dj < 5; ++dj) {
      short8v aw[5][2];                   // [di][hi/lo] for this wave's m
#pragma unroll
      for (int di = 0; di < 5; ++di) {
        const size_t e0 = (size_t)(((di * 5 + dj) * 8 + ch) * 4 + m * 2) * 64 + l;
        aw[di][0] = wf[e0];        // hi part
        aw[di][1] = wf[e0 + 64];   // lo part
      }
      __builtin_amdgcn_s_setprio(1);
#pragma unroll
      for (int rr = 0; rr < 8; ++rr) {
        const int t = wr * 4 + rr;
        const int c = l31 + dj;           // <= 35 < 40, in-bounds
        const short8v bh = *(const short8v*)&act[cur][0][t][c][q8];
        const short8v bl = *(const short8v*)&act[cur][1][t][c][q8];
#pragma unroll
        for (int di = 0; di < 5; ++di) {
          const int r = rr - di;
          if (r < 0 || r > 3) continue;   // compile-time after unroll
          acc[r] = __builtin_amdgcn_mfma_f32_32x32x16_bf16(aw[di][0], bh, acc[r], 0, 0, 0);
          acc[r] = __builtin_amdgcn_mfma_f32_32x32x16_bf16(aw[di][1], bh, acc[r], 0, 0, 0);
          acc[r] = __builtin_amdgcn_mfma_f32_32x32x16_bf16(aw[di][0], bl, acc[r], 0, 0, 0);
        }
      }
      __builtin_amdgcn_s_setprio(0);
    }
    asm volatile("s_waitcnt vmcnt(0)" ::: "memory");
    __syncthreads();
  }

  // ---- epilogue: bias + relu + store ----
  const int xg = x0 + l31;
  if (xg < WLON) {
#pragma unroll
    for (int r = 0; r < 4; ++r) {
      const int y = y0 + wr * 4 + r;
      if (y >= HLAT) continue;
#pragma unroll
      for (int e = 0; e < 16; ++e) {
        const int oc = m * 32 + (e & 3) + 8 * (e >> 2) + (q8 >> 1);
        h2[((size_t)(bi * 64 + oc) * HLAT + y) * WLON + xg] =
            fmaxf(acc[r][e] + b2[oc], 0.f);
      }
    }
  }
}

// ---------------- kernel 3: conv 64->3, 5x5, zero pad (f32, 8 px/thr) -----
// Tile 16 rows x 128 cols; thread = rows (ry, ry+8) x 4 cols. 288 blocks:
// halves the per-CU w3 LDS-broadcast traffic (1600 reads/wave is fixed).
__global__ __launch_bounds__(256, 2) void k_conv3(const float* __restrict__ h2,
    const float* __restrict__ w3t, const float* __restrict__ b3,
    float* __restrict__ out, int b0) {
  const int x0 = blockIdx.x * 128;
  const int y0 = blockIdx.y * 16;
  const int bi = blockIdx.z;
  __shared__ __align__(16) float s_w3[1600][4];    // 25600 B
  __shared__ __align__(16) float s_in[4][20][136]; // 43520 B
  const int tid = threadIdx.x;
  const int ry = tid >> 5;            // 0..7
  const int cx0 = (tid & 31) << 2;

  for (int idx = tid; idx < 1600; idx += 256)
    ((float4*)s_w3)[idx] = ((const float4*)w3t)[idx];

  float acc[3][2][4];
#pragma unroll
  for (int o = 0; o < 3; ++o)
#pragma unroll
    for (int rr = 0; rr < 2; ++rr)
#pragma unroll
      for (int p = 0; p < 4; ++p) acc[o][rr][p] = 0.f;

  for (int cc = 0; cc < 16; ++cc) {
    __syncthreads();
    for (int idx = tid; idx < 4 * 20 * 132; idx += 256) {
      const int ci = idx / (20 * 132);
      const int r = (idx / 132) % 20;
      const int col = idx % 132;
      const int yy = y0 + r - 2;
      const int xx = x0 + col - 2;
      float v = 0.f;
      if (yy >= 0 && yy < HLAT && xx >= 0 && xx < WLON)
        v = h2[((size_t)(bi * 64 + cc * 4 + ci) * HLAT + yy) * WLON + xx];
      s_in[ci][r][col] = v;
    }
    __syncthreads();
#pragma unroll
    for (int ci = 0; ci < 4; ++ci) {
#pragma unroll
      for (int i = 0; i < 5; ++i) {
        const float4 a4 = *(const float4*)&s_in[ci][ry + i][cx0];
        const float4 b4 = *(const float4*)&s_in[ci][ry + i][cx0 + 4];
        const float4 c4 = *(const float4*)&s_in[ci][ry + 8 + i][cx0];
        const float4 d4 = *(const float4*)&s_in[ci][ry + 8 + i][cx0 + 4];
        const float win0[8] = {a4.x, a4.y, a4.z, a4.w, b4.x, b4.y, b4.z, b4.w};
        const float win1[8] = {c4.x, c4.y, c4.z, c4.w, d4.x, d4.y, d4.z, d4.w};
#pragma unroll
        for (int j = 0; j < 5; ++j) {
          const float4 w4 = *(const float4*)&s_w3[(cc * 4 + ci) * 25 + i * 5 + j][0];
          const float wv3[3] = {w4.x, w4.y, w4.z};
#pragma unroll
          for (int p = 0; p < 4; ++p) {
            const float v0 = win0[j + p];
            const float v1 = win1[j + p];
#pragma unroll
            for (int o = 0; o < 3; ++o) {
              acc[o][0][p] += wv3[o] * v0;
              acc[o][1][p] += wv3[o] * v1;
            }
          }
        }
      }
    }
  }
  const int b = b0 + bi;
#pragma unroll
  for (int rr = 0; rr < 2; ++rr) {
    const int oy = y0 + ry + rr * 8;
    if (oy >= HLAT) continue;
#pragma unroll
    for (int o = 0; o < 3; ++o) {
      const float bb = b3[o];
      float* dst = out + ((size_t)(b * 3 + o) * HLAT + oy) * WLON;
#pragma unroll
      for (int p = 0; p < 4; ++p) {
        const int ox = x0 + cx0 + p;
        if (ox < WLON) dst[ox] = acc[o][rr][p] + bb;
      }
    }
  }
}

extern "C" void kernel_launch(void* const* d_in, const int* in_sizes, int n_in,
                              void* d_out, int out_size, void* d_ws, size_t ws_size,
                              hipStream_t stream) {
  const float* x    = (const float*)d_in[0];
  const float* psi  = (const float*)d_in[1];
  const float* quad = (const float*)d_in[2];
  const float* w1   = (const float*)d_in[3];
  const float* b1   = (const float*)d_in[4];
  const float* w2   = (const float*)d_in[5];
  const float* b2   = (const float*)d_in[6];
  const float* w3   = (const float*)d_in[7];
  const float* b3   = (const float*)d_in[8];
  float* out = (float*)d_out;
  float* ws  = (float*)d_ws;

  float*  w3t = ws;                       // 6400 floats
  ushort* w2f = (ushort*)(ws + 6400);     // 409600 ushorts (= 204800 floats)
  float*  w1t = ws + 211200;              // 3584 floats
  const size_t HEAD = 214784;             // floats

  size_t wsf = ws_size / 4;
  const size_t h1s_f = PCH * 8;           // floats per batch for 16 chunk-planes
  const size_t per_b = h1s_f + (size_t)64 * HW;
  int bc = 8;
  while (bc > 1 && HEAD + (size_t)bc * per_b > wsf) bc >>= 1;

  ushort* h1s = (ushort*)(ws + HEAD);
  float*  h2  = ws + HEAD + (size_t)bc * h1s_f;

  k_tw<<<dim3(200), dim3(256), 0, stream>>>(w2, w3, w1, w2f, w3t, w1t);
  k_zring<<<dim3(16, bc * 16), dim3(256), 0, stream>>>(h1s);

  for (int b0 = 0; b0 < 8; b0 += bc) {
    int cur = 8 - b0 < bc ? 8 - b0 : bc;
    k_l1<<<dim3(HLAT, cur), dim3(128), 0, stream>>>(x, psi, quad, w1t, b1, h1s, b0);
    k_conv2<<<dim3(12, 23, cur), dim3(256), 0, stream>>>(h1s, w2f, b2, h2);
    k_conv3<<<dim3(3, 12, cur), dim3(256), 0, stream>>>(h2, w3t, b3, out, b0);
  }
}

// Round 11
// 1028.191 us; speedup vs baseline: 1.3290x; 1.3290x over previous
//
#include <hip/hip_runtime.h>
#include <hip/hip_bf16.h>

#define HLAT 181
#define WLON 360
#define HW (HLAT * WLON)
#define HPAD 188
#define WPAD 368
#define PCH ((size_t)HPAD * WPAD * 16)   // ushorts per chunk-plane

typedef __attribute__((ext_vector_type(4)))  short short4v;
typedef __attribute__((ext_vector_type(8)))  short short8v;
typedef __attribute__((ext_vector_type(16))) float f32x16;

static __device__ __forceinline__ ushort bf16_hi_bits(float f) {
  union { float f; unsigned u; } c; c.f = f;
  unsigned u = c.u;
  unsigned rounded = u + 0x7FFF + ((u >> 16) & 1);  // RNE
  return (ushort)(rounded >> 16);
}
static __device__ __forceinline__ float bf16_to_f(ushort b) {
  union { unsigned u; float f; } c; c.u = ((unsigned)b) << 16;
  return c.f;
}

// ---------------- kernel 0: weight prep ----------------
// w2f entry idx = (tap*8+ch)*4 + m*2 + p ; each entry = 64 short8 (lane l)
//   lane l, j: part p of w2[oc=m*32+(l&31)][ci=ch*16+(l>>5)*8+j][tap]
// w1f entry idx = (m*2+kc)*2 + p ; lane l, j: part p of W1[oc=m*32+(l&31)][k]
//   where k = kc*16+(l>>5)*8+j; W1[o][k<27]=w1[o][k], W1[o][27]=b1[o], else 0.
// w3t[c*25+ij][4] (o=3 padded with 0).
__global__ __launch_bounds__(256) void k_tw(const float* __restrict__ w2,
                                            const float* __restrict__ w3,
                                            const float* __restrict__ w1,
                                            const float* __restrict__ b1,
                                            ushort* __restrict__ w2f,
                                            float* __restrict__ w3t,
                                            ushort* __restrict__ w1f) {
  int idx = blockIdx.x * 256 + threadIdx.x;
  if (idx < 51200) {
    int l   = idx & 63;
    int p   = (idx >> 6) & 1;
    int m   = (idx >> 7) & 1;
    int ch  = (idx >> 8) & 7;
    int tap = idx >> 11;
    int oc  = m * 32 + (l & 31);
    int ci0 = ch * 16 + (l >> 5) * 8;
#pragma unroll
    for (int j = 0; j < 8; ++j) {
      float f = w2[(oc * 128 + ci0 + j) * 25 + tap];
      ushort hi = bf16_hi_bits(f);
      ushort v;
      if (p == 0) v = hi;
      else        v = bf16_hi_bits(f - bf16_to_f(hi));
      w2f[(size_t)idx * 8 + j] = v;
    }
  }
  if (idx < 1600 * 4) {
    int ck = idx >> 2, o = idx & 3;
    int c = ck / 25, ij = ck % 25;
    w3t[idx] = (o < 3) ? w3[(o * 64 + c) * 25 + ij] : 0.f;
  }
  if (idx < 1024) {
    int l = idx & 63;
    int e = idx >> 6;          // 0..15
    int p  = e & 1;
    int kc = (e >> 1) & 1;
    int m  = e >> 2;
    int oc = m * 32 + (l & 31);
    int k0 = kc * 16 + (l >> 5) * 8;
#pragma unroll
    for (int j = 0; j < 8; ++j) {
      int k = k0 + j;
      float f = (k < 27) ? w1[oc * 27 + k] : (k == 27 ? b1[oc] : 0.f);
      ushort hi = bf16_hi_bits(f);
      ushort v;
      if (p == 0) v = hi;
      else        v = bf16_hi_bits(f - bf16_to_f(hi));
      w1f[(size_t)idx * 8 + j] = v;
    }
  }
}

// ---------------- zero ONLY the pad ring pixels (4024 per plane) ----------
__global__ __launch_bounds__(256) void k_zring(ushort* __restrict__ h1s) {
  const int i = blockIdx.x * 256 + threadIdx.x;
  if (i >= 4024) return;
  int row, col;
  if (i < 736)       { row = i / 368;              col = i % 368; }
  else if (i < 2576) { int p = i - 736;  row = 183 + p / 368; col = p % 368; }
  else if (i < 2938) { int p = i - 2576; row = 2 + p % 181;   col = p / 181; }
  else               { int p = i - 2938; row = 2 + p % 181;   col = 362 + p / 181; }
  short8v z = {0, 0, 0, 0, 0, 0, 0, 0};
  short8v* d = (short8v*)(h1s + (size_t)blockIdx.y * PCH + ((size_t)row * 368 + col) * 16);
  d[0] = z; d[1] = z;
}

// ---------------- kernel 1: disco conv (VALU) + w1 matvec (MFMA) ---------
// Block 256 (4 waves), grid (HLAT, bc). Threads 0..179 compute z[28] for
// px = tid, tid+180; z (+bias column k=27) -> LDS bf16 hi/lo B-frags.
// Then 4 waves x 3 px-frags x 4 m-frags of mfma_f32_32x32x16_bf16 (bf16x3).
// Epilogue: relu + hi/lo split + 8B-run stores into padded chunk planes.
__global__ __launch_bounds__(256, 2) void k_l1(const float* __restrict__ x,
    const float* __restrict__ psi, const float* __restrict__ quad,
    const ushort* __restrict__ w1f, ushort* __restrict__ h1s, int b0) {
  const int h = blockIdx.x;
  const int bi = blockIdx.y;
  const int b = b0 + bi;
  const int tid = threadIdx.x;
  __shared__ ushort zl[2][2][368][20];   // [part][kc][px][k8 pad20] = 58880 B

  if (tid < 180) {
    float z[2][28];
#pragma unroll
    for (int q = 0; q < 28; ++q) { z[0][q] = 0.f; z[1][q] = 0.f; }
#pragma unroll 1
    for (int i = 0; i < 5; ++i) {
      int hi = h + i - 2;
      hi = hi < 0 ? 0 : (hi >= HLAT ? HLAT - 1 : hi);
      const float qv = quad[hi];
      float pv[45];
#pragma unroll
      for (int kk = 0; kk < 9; ++kk)
#pragma unroll
        for (int j = 0; j < 5; ++j)
          pv[kk * 5 + j] = psi[((size_t)(kk * HLAT + h)) * 25 + i * 5 + j];
#pragma unroll
      for (int c = 0; c < 3; ++c) {
        const float* row = x + ((size_t)(b * 3 + c) * HLAT + hi) * WLON;
        float v0[5], v1[5];
#pragma unroll
        for (int j = 0; j < 5; ++j) {
          int wj0 = tid + j - 2; wj0 = wj0 < 0 ? wj0 + WLON : wj0;
          int wj1 = tid + 180 + j - 2; wj1 = wj1 >= WLON ? wj1 - WLON : wj1;
          v0[j] = row[wj0] * qv;
          v1[j] = row[wj1] * qv;
        }
#pragma unroll
        for (int kk = 0; kk < 9; ++kk) {
          float a0 = 0.f, a1 = 0.f;
#pragma unroll
          for (int j = 0; j < 5; ++j) {
            const float p = pv[kk * 5 + j];
            a0 += p * v0[j];
            a1 += p * v1[j];
          }
          z[0][c * 9 + kk] += a0;
          z[1][c * 9 + kk] += a1;
        }
      }
    }
    // convert + write B-fragments (bias column k=27 -> 1.0)
#pragma unroll
    for (int pp = 0; pp < 2; ++pp) {
      const int px = tid + pp * 180;
      z[pp][27] = 1.0f;
      ushort hiv[32], lov[32];
#pragma unroll
      for (int q = 0; q < 28; ++q) {
        const ushort hb = bf16_hi_bits(z[pp][q]);
        hiv[q] = hb;
        lov[q] = bf16_hi_bits(z[pp][q] - bf16_to_f(hb));
      }
#pragma unroll
      for (int q = 28; q < 32; ++q) { hiv[q] = 0; lov[q] = 0; }
#pragma unroll
      for (int kc = 0; kc < 2; ++kc) {
        union { ushort u[8]; short8v v; } ha, hbv, la, lb;
#pragma unroll
        for (int j = 0; j < 8; ++j) {
          ha.u[j] = hiv[kc * 16 + j];     hbv.u[j] = hiv[kc * 16 + 8 + j];
          la.u[j] = lov[kc * 16 + j];     lb.u[j]  = lov[kc * 16 + 8 + j];
        }
        *(short8v*)&zl[0][kc][px][0] = ha.v;
        *(short8v*)&zl[0][kc][px][8] = hbv.v;
        *(short8v*)&zl[1][kc][px][0] = la.v;
        *(short8v*)&zl[1][kc][px][8] = lb.v;
      }
    }
  } else {
    // zero the unused px rows 360..367 (read by masked lanes of frag 11)
    const int t2 = tid - 180;
    if (t2 < 32) {
      const int part = (t2 >> 4) & 1;
      const int kc = (t2 >> 3) & 1;
      const int px = 360 + (t2 & 7);
#pragma unroll
      for (int q = 0; q < 20; ++q) zl[part][kc][px][q] = 0;
    }
  }
  __syncthreads();

  const int wv = tid >> 6;
  const int l = tid & 63;
  const int l31 = l & 31;
  const int q = l >> 5;
  const short8v* wf1 = (const short8v*)w1f;
  short8v A[4][2][2];   // [m][kc][part]
#pragma unroll
  for (int m = 0; m < 4; ++m)
#pragma unroll
    for (int kc = 0; kc < 2; ++kc)
#pragma unroll
      for (int p = 0; p < 2; ++p)
        A[m][kc][p] = wf1[(size_t)(((m * 2 + kc) * 2 + p) * 64 + l)];

  ushort* base = h1s + (size_t)bi * 16 * PCH;
#pragma unroll
  for (int nn = 0; nn < 3; ++nn) {
    const int n = wv * 3 + nn;
    const int px = n * 32 + l31;
    const short8v bh0 = *(const short8v*)&zl[0][0][px][q * 8];
    const short8v bl0 = *(const short8v*)&zl[1][0][px][q * 8];
    const short8v bh1 = *(const short8v*)&zl[0][1][px][q * 8];
    const short8v bl1 = *(const short8v*)&zl[1][1][px][q * 8];
    const bool ok = px < 360;
    const size_t pixoff = ((size_t)(h + 2) * WPAD + (px + 2)) * 16;
#pragma unroll
    for (int m = 0; m < 4; ++m) {
      f32x16 acc;
#pragma unroll
      for (int e = 0; e < 16; ++e) acc[e] = 0.f;
      acc = __builtin_amdgcn_mfma_f32_32x32x16_bf16(A[m][0][0], bh0, acc, 0, 0, 0);
      acc = __builtin_amdgcn_mfma_f32_32x32x16_bf16(A[m][0][1], bh0, acc, 0, 0, 0);
      acc = __builtin_amdgcn_mfma_f32_32x32x16_bf16(A[m][0][0], bl0, acc, 0, 0, 0);
      acc = __builtin_amdgcn_mfma_f32_32x32x16_bf16(A[m][1][0], bh1, acc, 0, 0, 0);
      acc = __builtin_amdgcn_mfma_f32_32x32x16_bf16(A[m][1][1], bh1, acc, 0, 0, 0);
      acc = __builtin_amdgcn_mfma_f32_32x32x16_bf16(A[m][1][0], bl1, acc, 0, 0, 0);
      if (ok) {
#pragma unroll
        for (int r = 0; r < 4; ++r) {
          const int rb = 8 * r + 4 * q;       // oc-in-32 base of this run
          const int ch = m * 2 + (rb >> 4);   // 16-ci chunk plane
          const int ci0 = rb & 15;
          short4v h4, l4;
#pragma unroll
          for (int j = 0; j < 4; ++j) {
            const float v = fmaxf(acc[r * 4 + j], 0.f);
            const ushort hb = bf16_hi_bits(v);
            h4[j] = (short)hb;
            l4[j] = (short)bf16_hi_bits(v - bf16_to_f(hb));
          }
          *(short4v*)(base + (size_t)ch * PCH + pixoff + ci0) = h4;
          *(short4v*)(base + (size_t)(8 + ch) * PCH + pixoff + ci0) = l4;
        }
      }
    }
  }
}

// ---------------- kernel 2: conv 128->64 via bf16x3 MFMA (R9 form) --------
// grid (12, 23, bc) block 256 (4 waves = m-half x row-group).
// Tile: 64oc x 8rows x 32cols; wave = 32oc x 4rows x 32cols. 2 blocks/CU.
__global__ __launch_bounds__(256, 2) void k_conv2(const ushort* __restrict__ h1s,
    const ushort* __restrict__ w2f, const float* __restrict__ b2,
    float* __restrict__ h2) {
  __shared__ ushort act[2][2][12][40][16];  // [buf][part][row][col][ci16] = 61440 B
  const int x0 = blockIdx.x * 32;
  const int y0 = blockIdx.y * 8;
  const int bi = blockIdx.z;
  const int tid = threadIdx.x;
  const int wv = tid >> 6;
  const int m  = wv >> 1;         // oc half (0..1)
  const int wr = wv & 1;          // row-group (0..1)
  const int l = tid & 63;
  const int l31 = l & 31;
  const int q8 = (l >> 5) * 8;

  f32x16 acc[4];
#pragma unroll
  for (int r = 0; r < 4; ++r)
#pragma unroll
    for (int e = 0; e < 16; ++e) acc[r][e] = 0.f;

  const short8v* wf = (const short8v*)w2f;
  const ushort* pbase = h1s + (size_t)bi * 16 * PCH;

  auto stage = [&](int buf, int ch) {
#pragma unroll
    for (int s = 0; s < 12; ++s) {
      const int k = wv * 12 + s;          // 0..47
      const int part = k / 24;
      const int rem = k - part * 24;
      const int t = rem >> 1;             // row 0..11
      const int slot = rem & 1;
      const ushort* pl = pbase + (size_t)(part * 8 + ch) * PCH;
      if (slot == 0) {
        const ushort* g = pl + ((size_t)(y0 + t) * WPAD + (x0 + (l >> 1))) * 16 + (l & 1) * 8;
        __builtin_amdgcn_global_load_lds(
            (const __attribute__((address_space(1))) unsigned int*)g,
            (__attribute__((address_space(3))) unsigned int*)&act[buf][part][t][0][0], 16, 0, 0);
      } else {
        const ushort* g = pl + ((size_t)(y0 + t) * WPAD + (x0 + 32 + (l >> 3))) * 16 + (l & 7) * 2;
        __builtin_amdgcn_global_load_lds(
            (const __attribute__((address_space(1))) unsigned int*)g,
            (__attribute__((address_space(3))) unsigned int*)&act[buf][part][t][32][0], 4, 0, 0);
      }
    }
  };

  // prologue
  stage(0, 0);
  asm volatile("s_waitcnt vmcnt(0)" ::: "memory");
  __syncthreads();

#pragma unroll 1
  for (int ch = 0; ch < 8; ++ch) {
    const int cur = ch & 1;
    if (ch < 7) stage(cur ^ 1, ch + 1);   // prefetch next chunk (other buffer)
#pragma unroll 1
    for (int dj = 0; dj < 5; ++dj) {
      short8v aw[5][2];                   // [di][hi/lo] for this wave's m
#pragma unroll
      for (int di = 0; di < 5; ++di) {
        const size_t e0 = (size_t)(((di * 5 + dj) * 8 + ch) * 4 + m * 2) * 64 + l;
        aw[di][0] = wf[e0];        // hi part
        aw[di][1] = wf[e0 + 64];   // lo part
      }
      __builtin_amdgcn_s_setprio(1);
#pragma unroll
      for (int rr = 0; rr < 8; ++rr) {
        const int t = wr * 4 + rr;
        const int c = l31 + dj;           // <= 35 < 40, in-bounds
        const short8v bh = *(const short8v*)&act[cur][0][t][c][q8];
        const short8v bl = *(const short8v*)&act[cur][1][t][c][q8];
#pragma unroll
        for (int di = 0; di < 5; ++di) {
          const int r = rr - di;
          if (r < 0 || r > 3) continue;   // compile-time after unroll
          acc[r] = __builtin_amdgcn_mfma_f32_32x32x16_bf16(aw[di][0], bh, acc[r], 0, 0, 0);
          acc[r] = __builtin_amdgcn_mfma_f32_32x32x16_bf16(aw[di][1], bh, acc[r], 0, 0, 0);
          acc[r] = __builtin_amdgcn_mfma_f32_32x32x16_bf16(aw[di][0], bl, acc[r], 0, 0, 0);
        }
      }
      __builtin_amdgcn_s_setprio(0);
    }
    asm volatile("s_waitcnt vmcnt(0)" ::: "memory");
    __syncthreads();
  }

  // ---- epilogue: bias + relu + store ----
  const int xg = x0 + l31;
  if (xg < WLON) {
#pragma unroll
    for (int r = 0; r < 4; ++r) {
      const int y = y0 + wr * 4 + r;
      if (y >= HLAT) continue;
#pragma unroll
      for (int e = 0; e < 16; ++e) {
        const int oc = m * 32 + (e & 3) + 8 * (e >> 2) + (q8 >> 1);
        h2[((size_t)(bi * 64 + oc) * HLAT + y) * WLON + xg] =
            fmaxf(acc[r][e] + b2[oc], 0.f);
      }
    }
  }
}

// ---------------- kernel 3: conv 64->3, 5x5, zero pad (f32, R9 form) ------
__global__ __launch_bounds__(256) void k_conv3(const float* __restrict__ h2,
    const float* __restrict__ w3t, const float* __restrict__ b3,
    float* __restrict__ out, int b0) {
  const int x0 = blockIdx.x * 128;
  const int y0 = blockIdx.y * 8;
  const int bi = blockIdx.z;
  __shared__ __align__(16) float s_w3[1600][4];
  __shared__ __align__(16) float s_in[4][12][136];
  const int tid = threadIdx.x;
  const int ry = tid >> 5;
  const int cx0 = (tid & 31) << 2;

  for (int idx = tid; idx < 1600; idx += 256)
    ((float4*)s_w3)[idx] = ((const float4*)w3t)[idx];

  float acc[3][4];
#pragma unroll
  for (int o = 0; o < 3; ++o)
#pragma unroll
    for (int p = 0; p < 4; ++p) acc[o][p] = 0.f;

  for (int cc = 0; cc < 16; ++cc) {
    __syncthreads();
    for (int idx = tid; idx < 4 * 12 * 132; idx += 256) {
      const int ci = idx / (12 * 132);
      const int r = (idx / 132) % 12;
      const int col = idx % 132;
      const int yy = y0 + r - 2;
      const int xx = x0 + col - 2;
      float v = 0.f;
      if (yy >= 0 && yy < HLAT && xx >= 0 && xx < WLON)
        v = h2[((size_t)(bi * 64 + cc * 4 + ci) * HLAT + yy) * WLON + xx];
      s_in[ci][r][col] = v;
    }
    __syncthreads();
#pragma unroll
    for (int ci = 0; ci < 4; ++ci) {
#pragma unroll
      for (int i = 0; i < 5; ++i) {
        const float4 a4 = *(const float4*)&s_in[ci][ry + i][cx0];
        const float4 b4 = *(const float4*)&s_in[ci][ry + i][cx0 + 4];
        const float win[8] = {a4.x, a4.y, a4.z, a4.w, b4.x, b4.y, b4.z, b4.w};
#pragma unroll
        for (int j = 0; j < 5; ++j) {
          const float4 w4 = *(const float4*)&s_w3[(cc * 4 + ci) * 25 + i * 5 + j][0];
          const float wv3[3] = {w4.x, w4.y, w4.z};
#pragma unroll
          for (int p = 0; p < 4; ++p) {
            const float v = win[j + p];
#pragma unroll
            for (int o = 0; o < 3; ++o) acc[o][p] += wv3[o] * v;
          }
        }
      }
    }
  }
  const int oy = y0 + ry;
  const int b = b0 + bi;
  if (oy < HLAT) {
#pragma unroll
    for (int o = 0; o < 3; ++o) {
      const float bb = b3[o];
      float* dst = out + ((size_t)(b * 3 + o) * HLAT + oy) * WLON;
#pragma unroll
      for (int p = 0; p < 4; ++p) {
        const int ox = x0 + cx0 + p;
        if (ox < WLON) dst[ox] = acc[o][p] + bb;
      }
    }
  }
}

extern "C" void kernel_launch(void* const* d_in, const int* in_sizes, int n_in,
                              void* d_out, int out_size, void* d_ws, size_t ws_size,
                              hipStream_t stream) {
  const float* x    = (const float*)d_in[0];
  const float* psi  = (const float*)d_in[1];
  const float* quad = (const float*)d_in[2];
  const float* w1   = (const float*)d_in[3];
  const float* b1   = (const float*)d_in[4];
  const float* w2   = (const float*)d_in[5];
  const float* b2   = (const float*)d_in[6];
  const float* w3   = (const float*)d_in[7];
  const float* b3   = (const float*)d_in[8];
  float* out = (float*)d_out;
  float* ws  = (float*)d_ws;

  float*  w3t = ws;                       // 6400 floats
  ushort* w2f = (ushort*)(ws + 6400);     // 409600 ushorts (= 204800 floats)
  ushort* w1f = (ushort*)(ws + 211200);   // 8192 ushorts (= 4096 floats)
  const size_t HEAD = 215296;             // floats

  size_t wsf = ws_size / 4;
  const size_t h1s_f = PCH * 8;           // floats per batch for 16 chunk-planes
  const size_t per_b = h1s_f + (size_t)64 * HW;
  int bc = 8;
  while (bc > 1 && HEAD + (size_t)bc * per_b > wsf) bc >>= 1;

  ushort* h1s = (ushort*)(ws + HEAD);
  float*  h2  = ws + HEAD + (size_t)bc * h1s_f;

  k_tw<<<dim3(200), dim3(256), 0, stream>>>(w2, w3, w1, b1, w2f, w3t, w1f);
  k_zring<<<dim3(16, bc * 16), dim3(256), 0, stream>>>(h1s);

  for (int b0 = 0; b0 < 8; b0 += bc) {
    int cur = 8 - b0 < bc ? 8 - b0 : bc;
    k_l1<<<dim3(HLAT, cur), dim3(256), 0, stream>>>(x, psi, quad, w1f, h1s, b0);
    k_conv2<<<dim3(12, 23, cur), dim3(256), 0, stream>>>(h1s, w2f, b2, h2);
    k_conv3<<<dim3(3, 23, cur), dim3(256), 0, stream>>>(h2, w3t, b3, out, b0);
  }
}

// Round 13
// 746.349 us; speedup vs baseline: 1.8309x; 1.3776x over previous
//
#include <hip/hip_runtime.h>
#include <hip/hip_bf16.h>

#define HLAT 181
#define WLON 360
#define HW (HLAT * WLON)
#define HPAD 188
#define WPAD 368
#define PCH ((size_t)HPAD * WPAD * 16)        // ushorts per h1 chunk-plane
#define W2P 372
#define PLANE2 ((size_t)HPAD * W2P * 64)      // ushorts per h2 part-plane

typedef __attribute__((ext_vector_type(4)))  short short4v;
typedef __attribute__((ext_vector_type(8)))  short short8v;
typedef __attribute__((ext_vector_type(4)))  float f32x4;
typedef __attribute__((ext_vector_type(16))) float f32x16;

static __device__ __forceinline__ ushort bf16_hi_bits(float f) {
  union { float f; unsigned u; } c; c.f = f;
  unsigned u = c.u;
  unsigned rounded = u + 0x7FFF + ((u >> 16) & 1);  // RNE
  return (ushort)(rounded >> 16);
}
static __device__ __forceinline__ float bf16_to_f(ushort b) {
  union { unsigned u; float f; } c; c.u = ((unsigned)b) << 16;
  return c.f;
}

// ---------------- kernel 0: weight prep ----------------
// w2f entry idx = (tap*8+ch)*4 + m*2 + p ; lane l, j: part p of
//   w2[oc=m*32+(l&31)][ci=ch*16+(l>>5)*8+j][tap]     (32x32x16 A order)
// w1f entry idx = (m*2+kc)*2 + p ; lane l, j: part p of W1[oc=m*32+(l&31)][k]
//   k = kc*16+(l>>5)*8+j; W1[o][k<27]=w1, W1[o][27]=b1, else 0.
// w3f entry idx = (tap*2+kc)*2 + p ; lane l, j: part p of
//   W3[oc=l&15][ci=kc*32+(l>>4)*8+j][tap], oc>=3 -> 0   (16x16x32 A order)
__global__ __launch_bounds__(256) void k_tw(const float* __restrict__ w2,
                                            const float* __restrict__ w3,
                                            const float* __restrict__ w1,
                                            const float* __restrict__ b1,
                                            ushort* __restrict__ w2f,
                                            ushort* __restrict__ w1f,
                                            ushort* __restrict__ w3f) {
  int idx = blockIdx.x * 256 + threadIdx.x;
  if (idx < 51200) {
    int l   = idx & 63;
    int p   = (idx >> 6) & 1;
    int m   = (idx >> 7) & 1;
    int ch  = (idx >> 8) & 7;
    int tap = idx >> 11;
    int oc  = m * 32 + (l & 31);
    int ci0 = ch * 16 + (l >> 5) * 8;
#pragma unroll
    for (int j = 0; j < 8; ++j) {
      float f = w2[(oc * 128 + ci0 + j) * 25 + tap];
      ushort hi = bf16_hi_bits(f);
      w2f[(size_t)idx * 8 + j] = (p == 0) ? hi : bf16_hi_bits(f - bf16_to_f(hi));
    }
  }
  if (idx < 1024) {
    int l = idx & 63;
    int e = idx >> 6;
    int p  = e & 1;
    int kc = (e >> 1) & 1;
    int m  = e >> 2;
    int oc = m * 32 + (l & 31);
    int k0 = kc * 16 + (l >> 5) * 8;
#pragma unroll
    for (int j = 0; j < 8; ++j) {
      int k = k0 + j;
      float f = (k < 27) ? w1[oc * 27 + k] : (k == 27 ? b1[oc] : 0.f);
      ushort hi = bf16_hi_bits(f);
      w1f[(size_t)idx * 8 + j] = (p == 0) ? hi : bf16_hi_bits(f - bf16_to_f(hi));
    }
  }
  if (idx < 6400) {
    int l   = idx & 63;
    int p   = (idx >> 6) & 1;
    int kc  = (idx >> 7) & 1;
    int tap = idx >> 8;               // 0..24
    int oc  = l & 15;
    int ci0 = kc * 32 + (l >> 4) * 8;
#pragma unroll
    for (int j = 0; j < 8; ++j) {
      float f = (oc < 3) ? w3[(oc * 64 + ci0 + j) * 25 + tap] : 0.f;
      ushort hi = bf16_hi_bits(f);
      w3f[(size_t)idx * 8 + j] = (p == 0) ? hi : bf16_hi_bits(f - bf16_to_f(hi));
    }
  }
}

// ---------------- zero pad ring of h1 chunk-planes (4024 px each) ---------
__global__ __launch_bounds__(256) void k_zring(ushort* __restrict__ h1s) {
  const int i = blockIdx.x * 256 + threadIdx.x;
  if (i >= 4024) return;
  int row, col;
  if (i < 736)       { row = i / 368;              col = i % 368; }
  else if (i < 2576) { int p = i - 736;  row = 183 + p / 368; col = p % 368; }
  else if (i < 2938) { int p = i - 2576; row = 2 + p % 181;   col = p / 181; }
  else               { int p = i - 2938; row = 2 + p % 181;   col = 362 + p / 181; }
  short8v z = {0, 0, 0, 0, 0, 0, 0, 0};
  short8v* d = (short8v*)(h1s + (size_t)blockIdx.y * PCH + ((size_t)row * 368 + col) * 16);
  d[0] = z; d[1] = z;
}

// ---------------- zero pad ring of h2 part-planes (4776 px each) ----------
__global__ __launch_bounds__(256) void k_zring2(ushort* __restrict__ h2p) {
  const int i = blockIdx.x * 256 + threadIdx.x;
  if (i >= 4776) return;
  int row, col;
  if (i < 744)       { row = i / W2P;             col = i % W2P; }
  else if (i < 2604) { int p = i - 744;  row = 183 + p / W2P; col = p % W2P; }
  else               { int p = i - 2604; row = 2 + p % 181;
                       int cI = p / 181; col = (cI < 2) ? cI : 360 + cI; }
  short8v z = {0, 0, 0, 0, 0, 0, 0, 0};
  short8v* d = (short8v*)(h2p + (size_t)blockIdx.y * PLANE2 + ((size_t)row * W2P + col) * 64);
#pragma unroll
  for (int k = 0; k < 8; ++k) d[k] = z;
}

// ---------------- kernel 1: disco conv (VALU) + w1 matvec (MFMA) ---------
__global__ __launch_bounds__(256, 2) void k_l1(const float* __restrict__ x,
    const float* __restrict__ psi, const float* __restrict__ quad,
    const ushort* __restrict__ w1f, ushort* __restrict__ h1s, int b0) {
  const int h = blockIdx.x;
  const int bi = blockIdx.y;
  const int b = b0 + bi;
  const int tid = threadIdx.x;
  __shared__ ushort zl[2][2][368][20];   // [part][kc][px][k8 pad20] = 58880 B

  if (tid < 180) {
    float z[2][28];
#pragma unroll
    for (int q = 0; q < 28; ++q) { z[0][q] = 0.f; z[1][q] = 0.f; }
#pragma unroll 1
    for (int i = 0; i < 5; ++i) {
      int hi = h + i - 2;
      hi = hi < 0 ? 0 : (hi >= HLAT ? HLAT - 1 : hi);
      const float qv = quad[hi];
      float pv[45];
#pragma unroll
      for (int kk = 0; kk < 9; ++kk)
#pragma unroll
        for (int j = 0; j < 5; ++j)
          pv[kk * 5 + j] = psi[((size_t)(kk * HLAT + h)) * 25 + i * 5 + j];
#pragma unroll
      for (int c = 0; c < 3; ++c) {
        const float* row = x + ((size_t)(b * 3 + c) * HLAT + hi) * WLON;
        float v0[5], v1[5];
#pragma unroll
        for (int j = 0; j < 5; ++j) {
          int wj0 = tid + j - 2; wj0 = wj0 < 0 ? wj0 + WLON : wj0;
          int wj1 = tid + 180 + j - 2; wj1 = wj1 >= WLON ? wj1 - WLON : wj1;
          v0[j] = row[wj0] * qv;
          v1[j] = row[wj1] * qv;
        }
#pragma unroll
        for (int kk = 0; kk < 9; ++kk) {
          float a0 = 0.f, a1 = 0.f;
#pragma unroll
          for (int j = 0; j < 5; ++j) {
            const float p = pv[kk * 5 + j];
            a0 += p * v0[j];
            a1 += p * v1[j];
          }
          z[0][c * 9 + kk] += a0;
          z[1][c * 9 + kk] += a1;
        }
      }
    }
#pragma unroll
    for (int pp = 0; pp < 2; ++pp) {
      const int px = tid + pp * 180;
      z[pp][27] = 1.0f;
      ushort hiv[32], lov[32];
#pragma unroll
      for (int q = 0; q < 28; ++q) {
        const ushort hb = bf16_hi_bits(z[pp][q]);
        hiv[q] = hb;
        lov[q] = bf16_hi_bits(z[pp][q] - bf16_to_f(hb));
      }
#pragma unroll
      for (int q = 28; q < 32; ++q) { hiv[q] = 0; lov[q] = 0; }
#pragma unroll
      for (int kc = 0; kc < 2; ++kc) {
        union { ushort u[8]; short8v v; } ha, hbv, la, lb;
#pragma unroll
        for (int j = 0; j < 8; ++j) {
          ha.u[j] = hiv[kc * 16 + j];     hbv.u[j] = hiv[kc * 16 + 8 + j];
          la.u[j] = lov[kc * 16 + j];     lb.u[j]  = lov[kc * 16 + 8 + j];
        }
        *(short8v*)&zl[0][kc][px][0] = ha.v;
        *(short8v*)&zl[0][kc][px][8] = hbv.v;
        *(short8v*)&zl[1][kc][px][0] = la.v;
        *(short8v*)&zl[1][kc][px][8] = lb.v;
      }
    }
  } else {
    const int t2 = tid - 180;
    if (t2 < 32) {
      const int part = (t2 >> 4) & 1;
      const int kc = (t2 >> 3) & 1;
      const int px = 360 + (t2 & 7);
#pragma unroll
      for (int q = 0; q < 20; ++q) zl[part][kc][px][q] = 0;
    }
  }
  __syncthreads();

  const int wv = tid >> 6;
  const int l = tid & 63;
  const int l31 = l & 31;
  const int q = l >> 5;
  const short8v* wf1 = (const short8v*)w1f;
  short8v A[4][2][2];   // [m][kc][part]
#pragma unroll
  for (int m = 0; m < 4; ++m)
#pragma unroll
    for (int kc = 0; kc < 2; ++kc)
#pragma unroll
      for (int p = 0; p < 2; ++p)
        A[m][kc][p] = wf1[(size_t)(((m * 2 + kc) * 2 + p) * 64 + l)];

  ushort* base = h1s + (size_t)bi * 16 * PCH;
#pragma unroll
  for (int nn = 0; nn < 3; ++nn) {
    const int n = wv * 3 + nn;
    const int px = n * 32 + l31;
    const short8v bh0 = *(const short8v*)&zl[0][0][px][q * 8];
    const short8v bl0 = *(const short8v*)&zl[1][0][px][q * 8];
    const short8v bh1 = *(const short8v*)&zl[0][1][px][q * 8];
    const short8v bl1 = *(const short8v*)&zl[1][1][px][q * 8];
    const bool ok = px < 360;
    const size_t pixoff = ((size_t)(h + 2) * WPAD + (px + 2)) * 16;
#pragma unroll
    for (int m = 0; m < 4; ++m) {
      f32x16 acc;
#pragma unroll
      for (int e = 0; e < 16; ++e) acc[e] = 0.f;
      acc = __builtin_amdgcn_mfma_f32_32x32x16_bf16(A[m][0][0], bh0, acc, 0, 0, 0);
      acc = __builtin_amdgcn_mfma_f32_32x32x16_bf16(A[m][0][1], bh0, acc, 0, 0, 0);
      acc = __builtin_amdgcn_mfma_f32_32x32x16_bf16(A[m][0][0], bl0, acc, 0, 0, 0);
      acc = __builtin_amdgcn_mfma_f32_32x32x16_bf16(A[m][1][0], bh1, acc, 0, 0, 0);
      acc = __builtin_amdgcn_mfma_f32_32x32x16_bf16(A[m][1][1], bh1, acc, 0, 0, 0);
      acc = __builtin_amdgcn_mfma_f32_32x32x16_bf16(A[m][1][0], bl1, acc, 0, 0, 0);
      if (ok) {
#pragma unroll
        for (int r = 0; r < 4; ++r) {
          const int rb = 8 * r + 4 * q;
          const int ch = m * 2 + (rb >> 4);
          const int ci0 = rb & 15;
          short4v h4, l4;
#pragma unroll
          for (int j = 0; j < 4; ++j) {
            const float v = fmaxf(acc[r * 4 + j], 0.f);
            const ushort hb = bf16_hi_bits(v);
            h4[j] = (short)hb;
            l4[j] = (short)bf16_hi_bits(v - bf16_to_f(hb));
          }
          *(short4v*)(base + (size_t)ch * PCH + pixoff + ci0) = h4;
          *(short4v*)(base + (size_t)(8 + ch) * PCH + pixoff + ci0) = l4;
        }
      }
    }
  }
}

// ---------------- kernel 2: conv 128->64 via bf16x3 MFMA ------------------
// R9 core; epilogue writes h2 as bf16 hi/lo padded planes [y+2][x+2][64ci].
__global__ __launch_bounds__(256, 2) void k_conv2(const ushort* __restrict__ h1s,
    const ushort* __restrict__ w2f, const float* __restrict__ b2,
    ushort* __restrict__ h2p) {
  __shared__ ushort act[2][2][12][40][16];  // 61440 B
  const int x0 = blockIdx.x * 32;
  const int y0 = blockIdx.y * 8;
  const int bi = blockIdx.z;
  const int tid = threadIdx.x;
  const int wv = tid >> 6;
  const int m  = wv >> 1;
  const int wr = wv & 1;
  const int l = tid & 63;
  const int l31 = l & 31;
  const int q8 = (l >> 5) * 8;

  f32x16 acc[4];
#pragma unroll
  for (int r = 0; r < 4; ++r)
#pragma unroll
    for (int e = 0; e < 16; ++e) acc[r][e] = 0.f;

  const short8v* wf = (const short8v*)w2f;
  const ushort* pbase = h1s + (size_t)bi * 16 * PCH;

  auto stage = [&](int buf, int ch) {
#pragma unroll
    for (int s = 0; s < 12; ++s) {
      const int k = wv * 12 + s;
      const int part = k / 24;
      const int rem = k - part * 24;
      const int t = rem >> 1;
      const int slot = rem & 1;
      const ushort* pl = pbase + (size_t)(part * 8 + ch) * PCH;
      if (slot == 0) {
        const ushort* g = pl + ((size_t)(y0 + t) * WPAD + (x0 + (l >> 1))) * 16 + (l & 1) * 8;
        __builtin_amdgcn_global_load_lds(
            (const __attribute__((address_space(1))) unsigned int*)g,
            (__attribute__((address_space(3))) unsigned int*)&act[buf][part][t][0][0], 16, 0, 0);
      } else {
        const ushort* g = pl + ((size_t)(y0 + t) * WPAD + (x0 + 32 + (l >> 3))) * 16 + (l & 7) * 2;
        __builtin_amdgcn_global_load_lds(
            (const __attribute__((address_space(1))) unsigned int*)g,
            (__attribute__((address_space(3))) unsigned int*)&act[buf][part][t][32][0], 4, 0, 0);
      }
    }
  };

  stage(0, 0);
  asm volatile("s_waitcnt vmcnt(0)" ::: "memory");
  __syncthreads();

#pragma unroll 1
  for (int ch = 0; ch < 8; ++ch) {
    const int cur = ch & 1;
    if (ch < 7) stage(cur ^ 1, ch + 1);
#pragma unroll 1
    for (int dj = 0; dj < 5; ++dj) {
      short8v aw[5][2];
#pragma unroll
      for (int di = 0; di < 5; ++di) {
        const size_t e0 = (size_t)(((di * 5 + dj) * 8 + ch) * 4 + m * 2) * 64 + l;
        aw[di][0] = wf[e0];
        aw[di][1] = wf[e0 + 64];
      }
      __builtin_amdgcn_s_setprio(1);
#pragma unroll
      for (int rr = 0; rr < 8; ++rr) {
        const int t = wr * 4 + rr;
        const int c = l31 + dj;
        const short8v bh = *(const short8v*)&act[cur][0][t][c][q8];
        const short8v bl = *(const short8v*)&act[cur][1][t][c][q8];
#pragma unroll
        for (int di = 0; di < 5; ++di) {
          const int r = rr - di;
          if (r < 0 || r > 3) continue;
          acc[r] = __builtin_amdgcn_mfma_f32_32x32x16_bf16(aw[di][0], bh, acc[r], 0, 0, 0);
          acc[r] = __builtin_amdgcn_mfma_f32_32x32x16_bf16(aw[di][1], bh, acc[r], 0, 0, 0);
          acc[r] = __builtin_amdgcn_mfma_f32_32x32x16_bf16(aw[di][0], bl, acc[r], 0, 0, 0);
        }
      }
      __builtin_amdgcn_s_setprio(0);
    }
    asm volatile("s_waitcnt vmcnt(0)" ::: "memory");
    __syncthreads();
  }

  // ---- epilogue: bias + relu -> bf16 hi/lo padded planes ----
  // oc of acc element e: (e&3) + 8*(e>>2) + 4*(l>>5) + 32*m.
  // Run form (e = run*4+j): oc = j + 8*run + (q8>>1) + 32*m.
  const int xg = x0 + l31;
  ushort* hp = h2p + (size_t)bi * 2 * PLANE2;
  if (xg < WLON) {
#pragma unroll
    for (int r = 0; r < 4; ++r) {
      const int y = y0 + wr * 4 + r;
      if (y >= HLAT) continue;
      const size_t po = ((size_t)(y + 2) * W2P + (xg + 2)) * 64;
#pragma unroll
      for (int run = 0; run < 4; ++run) {
        const int oc0 = m * 32 + 8 * run + (q8 >> 1);   // FIXED (was 16*q)
        short4v h4, l4;
#pragma unroll
        for (int j = 0; j < 4; ++j) {
          const float v = fmaxf(acc[r][run * 4 + j] + b2[oc0 + j], 0.f);
          const ushort hb = bf16_hi_bits(v);
          h4[j] = (short)hb;
          l4[j] = (short)bf16_hi_bits(v - bf16_to_f(hb));
        }
        *(short4v*)(hp + po + oc0) = h4;
        *(short4v*)(hp + PLANE2 + po + oc0) = l4;
      }
    }
  }
}

// ---------------- kernel 3: conv 64->3 via bf16x3 MFMA (16x16x32) ---------
// grid (23, 23, bc) block 256 (4 waves = 4 row-groups of 2 rows).
// Tile 8 rows x 16 cols. Input tile (12x20 px x 64ci x 2 parts) reg-staged
// into CI-padded LDS [20][72] (pad kills the 16-way bank conflict).
__global__ __launch_bounds__(256, 2) void k_conv3(const ushort* __restrict__ h2p,
    const ushort* __restrict__ w3f, const float* __restrict__ b3,
    float* __restrict__ out, int b0) {
  __shared__ ushort act[2][12][20][72];   // 69120 B
  const int x0 = blockIdx.x * 16;
  const int y0 = blockIdx.y * 8;
  const int bi = blockIdx.z;
  const int tid = threadIdx.x;
  const int wv = tid >> 6;
  const int l = tid & 63;

  // ---- stage: 6 (part,row) pairs per wave; 2560B real data per pair ----
  {
    const ushort* pb = h2p + (size_t)bi * 2 * PLANE2;
    float4 v[6][3];
#pragma unroll
    for (int pr = 0; pr < 6; ++pr) {
      const int pair = wv * 6 + pr;
      const int part = pair / 12;
      const int row = pair % 12;
      const ushort* src = pb + (size_t)part * PLANE2 +
                          ((size_t)(y0 + row) * W2P + x0) * 64;
      v[pr][0] = *(const float4*)((const char*)src + l * 16);
      v[pr][1] = *(const float4*)((const char*)src + 1024 + l * 16);
      if (l < 32) v[pr][2] = *(const float4*)((const char*)src + 2048 + l * 16);
    }
#pragma unroll
    for (int pr = 0; pr < 6; ++pr) {
      const int pair = wv * 6 + pr;
      const int part = pair / 12;
      const int row = pair % 12;
#pragma unroll
      for (int k2 = 0; k2 < 3; ++k2) {
        if (k2 == 2 && l >= 32) continue;
        const int B = k2 * 1024 + l * 16;
        const int col = B >> 7;
        const int ci = (B & 127) >> 1;       // ushort index
        *(short8v*)&act[part][row][col][ci] = *(short8v*)&v[pr][k2];
      }
    }
  }
  __syncthreads();

  f32x4 acc[2];
#pragma unroll
  for (int r = 0; r < 2; ++r)
#pragma unroll
    for (int e = 0; e < 4; ++e) acc[r][e] = 0.f;

  const short8v* wf3 = (const short8v*)w3f;
  const int c16 = l & 15;
  const int koff0 = ((l >> 4) & 3) * 8;

#pragma unroll 1
  for (int kc = 0; kc < 2; ++kc) {
#pragma unroll 1
    for (int dj = 0; dj < 5; ++dj) {
      short8v A[5][2];
#pragma unroll
      for (int di = 0; di < 5; ++di) {
        const size_t e0 = (size_t)(((di * 5 + dj) * 2 + kc) * 2) * 64 + l;
        A[di][0] = wf3[e0];
        A[di][1] = wf3[e0 + 64];
      }
      const int c = c16 + dj;
      const int koff = kc * 32 + koff0;
      __builtin_amdgcn_s_setprio(1);
#pragma unroll
      for (int tt = 0; tt < 6; ++tt) {
        const int t = wv * 2 + tt;
        const short8v bh = *(const short8v*)&act[0][t][c][koff];
        const short8v bl = *(const short8v*)&act[1][t][c][koff];
#pragma unroll
        for (int di = 0; di < 5; ++di) {
          const int r = tt - di;
          if (r < 0 || r > 1) continue;
          acc[r] = __builtin_amdgcn_mfma_f32_16x16x32_bf16(A[di][0], bh, acc[r], 0, 0, 0);
          acc[r] = __builtin_amdgcn_mfma_f32_16x16x32_bf16(A[di][1], bh, acc[r], 0, 0, 0);
          acc[r] = __builtin_amdgcn_mfma_f32_16x16x32_bf16(A[di][0], bl, acc[r], 0, 0, 0);
        }
      }
      __builtin_amdgcn_s_setprio(0);
    }
  }

  // ---- epilogue: only lanes 0..15 (C rows 0..3), regs j=0..2 = oc ----
  const int px = x0 + c16;
  const int b = b0 + bi;
  if ((l >> 4) == 0 && px < WLON) {
    const float bb[3] = {b3[0], b3[1], b3[2]};
#pragma unroll
    for (int r = 0; r < 2; ++r) {
      const int y = y0 + wv * 2 + r;
      if (y >= HLAT) continue;
#pragma unroll
      for (int j = 0; j < 3; ++j)
        out[((size_t)(b * 3 + j) * HLAT + y) * WLON + px] = acc[r][j] + bb[j];
    }
  }
}

extern "C" void kernel_launch(void* const* d_in, const int* in_sizes, int n_in,
                              void* d_out, int out_size, void* d_ws, size_t ws_size,
                              hipStream_t stream) {
  const float* x    = (const float*)d_in[0];
  const float* psi  = (const float*)d_in[1];
  const float* quad = (const float*)d_in[2];
  const float* w1   = (const float*)d_in[3];
  const float* b1   = (const float*)d_in[4];
  const float* w2   = (const float*)d_in[5];
  const float* b2   = (const float*)d_in[6];
  const float* w3   = (const float*)d_in[7];
  const float* b3   = (const float*)d_in[8];
  float* out = (float*)d_out;
  float* ws  = (float*)d_ws;

  ushort* w2f = (ushort*)ws;              // 409600 ushorts = 204800 fl
  ushort* w1f = (ushort*)(ws + 204800);   // 8192 ushorts   = 4096 fl
  ushort* w3f = (ushort*)(ws + 208896);   // 51200 ushorts  = 25600 fl
  const size_t HEAD = 234496;             // floats

  size_t wsf = ws_size / 4;
  const size_t h1s_f = PCH * 8;           // floats: 16 chunk-planes per batch
  const size_t h2p_f = PLANE2;            // floats: 2 part-planes per batch
  const size_t per_b = h1s_f + h2p_f;
  int bc = 8;
  while (bc > 1 && HEAD + (size_t)bc * per_b > wsf) bc >>= 1;

  ushort* h1s = (ushort*)(ws + HEAD);
  ushort* h2p = (ushort*)(ws + HEAD + (size_t)bc * h1s_f);

  k_tw<<<dim3(200), dim3(256), 0, stream>>>(w2, w3, w1, b1, w2f, w1f, w3f);
  k_zring<<<dim3(16, bc * 16), dim3(256), 0, stream>>>(h1s);
  k_zring2<<<dim3(19, bc * 2), dim3(256), 0, stream>>>(h2p);

  for (int b0 = 0; b0 < 8; b0 += bc) {
    int cur = 8 - b0 < bc ? 8 - b0 : bc;
    k_l1<<<dim3(HLAT, cur), dim3(256), 0, stream>>>(x, psi, quad, w1f, h1s, b0);
    k_conv2<<<dim3(12, 23, cur), dim3(256), 0, stream>>>(h1s, w2f, b2, h2p);
    k_conv3<<<dim3(23, 23, cur), dim3(256), 0, stream>>>(h2p, w3f, b3, out, b0);
  }
}